// Round 1
// baseline (1603.398 us; speedup 1.0000x reference)
//
#include <hip/hip_runtime.h>
#include <cstdint>
#include <cstddef>

#define NN 20000      // nodes
#define NE 640000     // edges
#define DD 128        // feature dim
#define NP 10000      // products (output cols)
#define KO 256        // 2*DD

typedef __attribute__((ext_vector_type(8))) short short8;
typedef __attribute__((ext_vector_type(4))) float f32x4;

static __device__ __forceinline__ unsigned short f2bf(float f){
  uint32_t u = __float_as_uint(f);
  uint32_t r = (u + 0x7fffu + ((u >> 16) & 1u)) >> 16;
  return (unsigned short)r;
}

__global__ void k_count(const int* __restrict__ dst, int* __restrict__ cnt, int n){
  int i = blockIdx.x * blockDim.x + threadIdx.x;
  if (i < n) atomicAdd(&cnt[dst[i]], 1);
}

__global__ void k_dinv(const int* __restrict__ cnt, float* __restrict__ dinv, int n){
  int i = blockIdx.x * blockDim.x + threadIdx.x;
  if (i < n) dinv[i] = rsqrtf((float)(cnt[i] + 1));  // +1 self-loop
}

// single-block exclusive scan over 20000 counts -> row offsets + cursor copy
__global__ void k_scan(const int* __restrict__ cnt, int* __restrict__ row_off,
                       int* __restrict__ cursor, int n){
  __shared__ int part[1024];
  int t = threadIdx.x;
  int per = (n + 1023) >> 10;
  int base = t * per;
  int s = 0;
  for (int i = 0; i < per; i++){ int idx = base + i; if (idx < n) s += cnt[idx]; }
  part[t] = s;
  __syncthreads();
  for (int off = 1; off < 1024; off <<= 1){
    int v = (t >= off) ? part[t - off] : 0;
    __syncthreads();
    part[t] += v;
    __syncthreads();
  }
  int run = (t == 0) ? 0 : part[t - 1];
  for (int i = 0; i < per; i++){
    int idx = base + i;
    if (idx < n){ row_off[idx] = run; cursor[idx] = run; run += cnt[idx]; }
  }
  if (t == 0) row_off[n] = part[1023];
}

__global__ void k_fill(const int* __restrict__ src, const int* __restrict__ dst,
                       int* __restrict__ cursor, int* __restrict__ col, int n){
  int i = blockIdx.x * blockDim.x + threadIdx.x;
  if (i < n){
    int p = atomicAdd(&cursor[dst[i]], 1);
    col[p] = src[i];
  }
}

__global__ void k_gather(const float* __restrict__ tab, const int* __restrict__ ids,
                         unsigned short* __restrict__ x, int total){
  int i = blockIdx.x * blockDim.x + threadIdx.x;
  if (i >= total) return;
  int n = i >> 7, d = i & 127;
  x[i] = f2bf(tab[(size_t)ids[n] * DD + d]);
}

// W [K][N] f32 -> Wt [N][K] bf16 (tiled transpose-cast)
__global__ void k_tcast(const float* __restrict__ W, unsigned short* __restrict__ Wt,
                        int K, int N){
  __shared__ float tile[32][33];
  int kb = blockIdx.y << 5, nb = blockIdx.x << 5;
  int tx = threadIdx.x, ty = threadIdx.y;
  int k = kb + ty, n = nb + tx;
  tile[ty][tx] = (k < K && n < N) ? W[(size_t)k * N + n] : 0.f;
  __syncthreads();
  int wn = nb + ty, wk = kb + tx;
  if (wn < N && wk < K) Wt[(size_t)wn * K + wk] = f2bf(tile[tx][ty]);
}

// out[n] = dinv[n]*(sum_e dinv[src]*h[src] + dinv[n]*h[n]) + b   -> bf16
__global__ void k_agg(const float* __restrict__ h, const float* __restrict__ dinv,
                      const int* __restrict__ row_off, const int* __restrict__ col,
                      const float* __restrict__ b, unsigned short* __restrict__ xout,
                      int ldx, int xoff, int nn){
  int node = blockIdx.x * blockDim.y + threadIdx.y;
  int d = threadIdx.x;
  if (node >= nn) return;
  float dn = dinv[node];
  float acc = dn * h[(size_t)node * DD + d];
  int s = row_off[node], e = row_off[node + 1];
  for (int i = s; i < e; i++){
    int sc = col[i];
    acc += dinv[sc] * h[(size_t)sc * DD + d];
  }
  float o = dn * acc + b[d];
  xout[(size_t)node * ldx + xoff + d] = f2bf(o);
}

static __device__ __forceinline__ void gload_lds16(const void* g, void* l){
  __builtin_amdgcn_global_load_lds(
      (const __attribute__((address_space(1))) void*)g,
      (__attribute__((address_space(3))) void*)l, 16, 0, 0);
}

// C = A(bf16 [M][K]) x Bt(bf16 [N][K])^T, fp32 accum.
// MODE 0: C[m][n] = acc (ldc=N).  MODE 1: C=exp(acc+bias[n]), atomic rowsum.
template<int MODE>
__global__ __launch_bounds__(256) void k_gemm(
    const unsigned short* __restrict__ A, const unsigned short* __restrict__ Bt,
    const float* __restrict__ bias, float* __restrict__ C, float* __restrict__ rowsum,
    int M, int N, int K){
  constexpr int BM = 128, BN = 128, BK = 64;
  __shared__ unsigned short sA[BM * BK];
  __shared__ unsigned short sB[BN * BK];
  const int tid = threadIdx.x;
  const int lane = tid & 63;
  const int wid = tid >> 6;
  const int row0 = blockIdx.x * BM, col0 = blockIdx.y * BN;
  const int wm = wid >> 1, wn = wid & 1;

  f32x4 acc[4][4] = {};

  const int st_row = lane >> 3;        // + c*8
  const int st_col = (lane & 7) * 8;
  const int fr = lane & 15;
  const int ko8 = (lane >> 4) * 8;

  for (int k0 = 0; k0 < K; k0 += BK){
    #pragma unroll
    for (int i = 0; i < 4; i++){
      int c = wid * 4 + i;
      int r = c * 8 + st_row;
      int ga = min(row0 + r, M - 1);
      gload_lds16(A + (size_t)ga * K + k0 + st_col, (void*)&sA[c * 512]);
      int gb = min(col0 + r, N - 1);
      gload_lds16(Bt + (size_t)gb * K + k0 + st_col, (void*)&sB[c * 512]);
    }
    __syncthreads();
    #pragma unroll
    for (int kk = 0; kk < BK; kk += 32){
      short8 av[4], bv[4];
      #pragma unroll
      for (int m = 0; m < 4; m++)
        av[m] = *reinterpret_cast<const short8*>(&sA[(wm * 64 + m * 16 + fr) * BK + kk + ko8]);
      #pragma unroll
      for (int n = 0; n < 4; n++)
        bv[n] = *reinterpret_cast<const short8*>(&sB[(wn * 64 + n * 16 + fr) * BK + kk + ko8]);
      #pragma unroll
      for (int m = 0; m < 4; m++)
        #pragma unroll
        for (int n = 0; n < 4; n++)
          acc[m][n] = __builtin_amdgcn_mfma_f32_16x16x32_bf16(av[m], bv[n], acc[m][n], 0, 0, 0);
    }
    __syncthreads();
  }

  const int fq = lane >> 4;
  if (MODE == 0){
    #pragma unroll
    for (int m = 0; m < 4; m++)
      #pragma unroll
      for (int n = 0; n < 4; n++)
        #pragma unroll
        for (int r = 0; r < 4; r++){
          int grow = row0 + wm * 64 + m * 16 + fq * 4 + r;
          int gcol = col0 + wn * 64 + n * 16 + fr;
          if (grow < M && gcol < N) C[(size_t)grow * N + gcol] = acc[m][n][r];
        }
  } else {
    #pragma unroll
    for (int m = 0; m < 4; m++)
      #pragma unroll
      for (int r = 0; r < 4; r++){
        int grow = row0 + wm * 64 + m * 16 + fq * 4 + r;
        float s = 0.f;
        #pragma unroll
        for (int n = 0; n < 4; n++){
          int gcol = col0 + wn * 64 + n * 16 + fr;
          float e = 0.f;
          if (grow < M && gcol < N){
            e = __expf(acc[m][n][r] + bias[gcol]);
            C[(size_t)grow * N + gcol] = e;
          }
          s += e;
        }
        #pragma unroll
        for (int off = 1; off < 16; off <<= 1) s += __shfl_xor(s, off, 64);
        if (fr == 0 && grow < M) atomicAdd(&rowsum[grow], s);
      }
  }
}

__global__ void k_recip(const float* __restrict__ rowsum, float* __restrict__ recip, int n){
  int i = blockIdx.x * blockDim.x + threadIdx.x;
  if (i < n) recip[i] = 1.0f / rowsum[i];
}

__global__ void k_scale(float* __restrict__ out, const float* __restrict__ recip){
  int row = blockIdx.y;
  int c4 = blockIdx.x * blockDim.x + threadIdx.x;
  if (c4 >= NP / 4) return;
  float r = recip[row];
  float4* p = reinterpret_cast<float4*>(out + (size_t)row * NP) + c4;
  float4 v = *p;
  v.x *= r; v.y *= r; v.z *= r; v.w *= r;
  *p = v;
}

extern "C" void kernel_launch(void* const* d_in, const int* in_sizes, int n_in,
                              void* d_out, int out_size, void* d_ws, size_t ws_size,
                              hipStream_t stream){
  const int*   user_ids = (const int*)d_in[0];
  const int*   prod_ids = (const int*)d_in[1];
  const int*   ei_u     = (const int*)d_in[2];   // [2][NE]: src, dst
  const int*   ei_p     = (const int*)d_in[3];
  const float* utab     = (const float*)d_in[4];
  const float* ptab     = (const float*)d_in[5];
  const float* uW       = (const float*)d_in[6]; // [2][128][128]
  const float* ub       = (const float*)d_in[7]; // [2][128]
  const float* pW       = (const float*)d_in[8];
  const float* pb       = (const float*)d_in[9];
  const float* oW       = (const float*)d_in[10]; // [256][10000]
  const float* ob       = (const float*)d_in[11]; // [10000]
  float* out = (float*)d_out;

  char* w = (char*)d_ws;
  size_t off = 0;
  auto alloc = [&](size_t bytes)->void*{
    void* p = w + off; off += (bytes + 255) & ~(size_t)255; return p;
  };
  int*   cnt_u  = (int*)alloc(NN * 4);
  int*   cnt_p  = (int*)alloc(NN * 4);
  float* dinv_u = (float*)alloc(NN * 4);
  float* dinv_p = (float*)alloc(NN * 4);
  int*   ro_u   = (int*)alloc((NN + 1) * 4);
  int*   ro_p   = (int*)alloc((NN + 1) * 4);
  int*   cur_u  = (int*)alloc(NN * 4);
  int*   cur_p  = (int*)alloc(NN * 4);
  int*   col_u  = (int*)alloc((size_t)NE * 4);
  int*   col_p  = (int*)alloc((size_t)NE * 4);
  unsigned short* xu   = (unsigned short*)alloc((size_t)NN * DD * 2);
  unsigned short* xp   = (unsigned short*)alloc((size_t)NN * DD * 2);
  float* h    = (float*)alloc((size_t)NN * DD * 4);
  unsigned short* comb = (unsigned short*)alloc((size_t)NN * KO * 2);
  unsigned short* WtS  = (unsigned short*)alloc((size_t)DD * DD * 2);
  unsigned short* WtO  = (unsigned short*)alloc((size_t)NP * KO * 2);
  float* rowsum = (float*)alloc(NN * 4);
  float* recip  = (float*)alloc(NN * 4);
  (void)ws_size; (void)in_sizes; (void)n_in; (void)out_size;

  hipMemsetAsync(cnt_u, 0, NN * 4, stream);
  hipMemsetAsync(cnt_p, 0, NN * 4, stream);
  hipMemsetAsync(rowsum, 0, NN * 4, stream);

  const int* src_u = ei_u;       const int* dst_u = ei_u + NE;
  const int* src_p = ei_p;       const int* dst_p = ei_p + NE;

  // CSR + dinv for both graphs
  k_count<<<(NE + 255) / 256, 256, 0, stream>>>(dst_u, cnt_u, NE);
  k_count<<<(NE + 255) / 256, 256, 0, stream>>>(dst_p, cnt_p, NE);
  k_dinv<<<(NN + 255) / 256, 256, 0, stream>>>(cnt_u, dinv_u, NN);
  k_dinv<<<(NN + 255) / 256, 256, 0, stream>>>(cnt_p, dinv_p, NN);
  k_scan<<<1, 1024, 0, stream>>>(cnt_u, ro_u, cur_u, NN);
  k_scan<<<1, 1024, 0, stream>>>(cnt_p, ro_p, cur_p, NN);
  k_fill<<<(NE + 255) / 256, 256, 0, stream>>>(src_u, dst_u, cur_u, col_u, NE);
  k_fill<<<(NE + 255) / 256, 256, 0, stream>>>(src_p, dst_p, cur_p, col_p, NE);

  // embedding gather -> bf16
  k_gather<<<(NN * DD + 255) / 256, 256, 0, stream>>>(utab, user_ids, xu, NN * DD);
  k_gather<<<(NN * DD + 255) / 256, 256, 0, stream>>>(ptab, prod_ids, xp, NN * DD);

  dim3 tblk(32, 32);
  dim3 gemmBlkConv(157, 1);
  dim3 aggGrid((NN + 1) / 2);
  dim3 aggBlk(128, 2);

  for (int L = 0; L < 2; L++){
    unsigned short* xu_out = (L == 0) ? xu : comb;
    unsigned short* xp_out = (L == 0) ? xp : comb;
    int ldx = (L == 0) ? DD : KO;
    int xoff_p = (L == 0) ? 0 : DD;
    // user tower
    k_tcast<<<dim3(4, 4), tblk, 0, stream>>>(uW + (size_t)L * DD * DD, WtS, DD, DD);
    k_gemm<0><<<gemmBlkConv, 256, 0, stream>>>(xu, WtS, nullptr, h, nullptr, NN, DD, DD);
    k_agg<<<aggGrid, aggBlk, 0, stream>>>(h, dinv_u, ro_u, col_u, ub + (size_t)L * DD,
                                          xu_out, ldx, 0, NN);
    // product tower
    k_tcast<<<dim3(4, 4), tblk, 0, stream>>>(pW + (size_t)L * DD * DD, WtS, DD, DD);
    k_gemm<0><<<gemmBlkConv, 256, 0, stream>>>(xp, WtS, nullptr, h, nullptr, NN, DD, DD);
    k_agg<<<aggGrid, aggBlk, 0, stream>>>(h, dinv_p, ro_p, col_p, pb + (size_t)L * DD,
                                          xp_out, ldx, xoff_p, NN);
  }

  // out_W [256][10000] -> WtO [10000][256] bf16
  k_tcast<<<dim3((NP + 31) / 32, (KO + 31) / 32), tblk, 0, stream>>>(oW, WtO, KO, NP);

  // pass 1: out = exp(comb @ WtO^T + ob), rowsum accumulated
  k_gemm<1><<<dim3((NN + 127) / 128, (NP + 127) / 128), 256, 0, stream>>>(
      comb, WtO, ob, out, rowsum, NN, NP, KO);

  // pass 2: normalize
  k_recip<<<(NN + 255) / 256, 256, 0, stream>>>(rowsum, recip, NN);
  k_scale<<<dim3((NP / 4 + 255) / 256, NN), 256, 0, stream>>>(out, recip);
}